// Round 1
// baseline (18486.391 us; speedup 1.0000x reference)
//
// Encoder-decoder LSTM + dot attention + linear, MI355X fp32.
// Design notes (R1):
//  - decoder LSTM state is independent of attention -> scan then batch attention
//  - out = softmax(S)·ew + hx·w2 + b  where ew[b][te]=E[b,te]·w1  (ctx GEMM collapsed)
//  - scan: 1 block / batch chain, 1024 thr (thread j = gate j), h in LDS, WhhT streamed from L2
//  - attention: block = (b, 16 td rows), online weighted softmax, scalars only
#include <hip/hip_runtime.h>
#include <math.h>

#define HD 256
#define GD 1024   // 4*H
#define TT 1024
#define BB 64

__device__ __forceinline__ float sig_(float x)  { return 1.f / (1.f + expf(-x)); }
__device__ __forceinline__ float tanh_(float x) { return tanhf(x); }

// ---------------- prep: transpose Whh -> [k][j], bias sums ----------------
__global__ __launch_bounds__(256) void prep_kernel(
    const float* __restrict__ eW, const float* __restrict__ eb1, const float* __restrict__ eb2,
    const float* __restrict__ dW, const float* __restrict__ db1, const float* __restrict__ db2,
    float* __restrict__ WTe, float* __restrict__ WTd,
    float* __restrict__ be, float* __restrict__ bd)
{
    int idx = blockIdx.x * 256 + threadIdx.x;
    if (idx < GD * HD) {
        int j = idx / HD, k = idx % HD;      // Whh[j][k]
        WTe[k * GD + j] = eW[idx];
        WTd[k * GD + j] = dW[idx];
    }
    if (idx < GD) {
        be[idx] = eb1[idx] + eb2[idx];
        bd[idx] = db1[idx] + db2[idx];
    }
}

// ---------------- LSTM scan: one block per batch chain ----------------
__global__ __launch_bounds__(1024) void lstm_scan_kernel(
    const float* __restrict__ x,       // [B,T]
    const float* __restrict__ Wih,     // [4H]
    const float* __restrict__ bias,    // [4H] (bih+bhh)
    const float* __restrict__ WT,      // [H][4H]
    const float* __restrict__ h_init,  // [B,H] or nullptr
    float* __restrict__ states,        // [B,T,H]
    float* __restrict__ h_last)        // [B,H] or nullptr
{
    const int b = blockIdx.x;
    const int j = threadIdx.x;          // gate index 0..1023
    __shared__ float h_s[HD];
    __shared__ float g_s[GD];

    if (j < HD) h_s[j] = h_init ? h_init[b * HD + j] : 0.f;
    float c = 0.f;
    const float wih = Wih[j];
    const float bj  = bias[j];
    const int gate  = j >> 8;           // 0:i 1:f 2:g 3:o
    const float* __restrict__ wp = WT + j;
    __syncthreads();

    for (int t = 0; t < TT; ++t) {
        const float xt = x[b * TT + t];
        float acc = fmaf(xt, wih, bj);
        #pragma unroll 16
        for (int k = 0; k < HD; ++k)
            acc = fmaf(h_s[k], wp[(size_t)k * GD], acc);
        g_s[j] = (gate == 2) ? tanh_(acc) : sig_(acc);
        __syncthreads();
        if (j < HD) {
            float gi = g_s[j], gf = g_s[j + HD], gg = g_s[j + 2 * HD], go = g_s[j + 3 * HD];
            c = fmaf(gf, c, gi * gg);
            float h = go * tanh_(c);
            h_s[j] = h;
            states[((size_t)b * TT + t) * HD + j] = h;
        }
        __syncthreads();
    }
    if (h_last != nullptr && j < HD) h_last[b * HD + j] = h_s[j];
}

// ---------------- proj: ew[b][t]=E·w1, hw[b][t]=Hx·w2 (one wave per row) ----------------
__global__ __launch_bounds__(256) void proj_kernel(
    const float* __restrict__ enc_states, const float* __restrict__ dec_hs,
    const float* __restrict__ linW, float* __restrict__ ew, float* __restrict__ hw)
{
    const int lane = threadIdx.x & 63;
    const int wid  = blockIdx.x * 4 + (threadIdx.x >> 6);
    const int nw   = gridDim.x * 4;
    const float4 w1 = ((const float4*)linW)[lane];
    const float4 w2 = ((const float4*)(linW + HD))[lane];
    for (int o = wid; o < BB * TT; o += nw) {
        float4 v1 = ((const float4*)(enc_states + (size_t)o * HD))[lane];
        float4 v2 = ((const float4*)(dec_hs     + (size_t)o * HD))[lane];
        float s1 = v1.x * w1.x + v1.y * w1.y + v1.z * w1.z + v1.w * w1.w;
        float s2 = v2.x * w2.x + v2.y * w2.y + v2.z * w2.z + v2.w * w2.w;
        #pragma unroll
        for (int m = 1; m < 64; m <<= 1) {
            s1 += __shfl_xor(s1, m);
            s2 += __shfl_xor(s2, m);
        }
        if (lane == 0) { ew[o] = s1; hw[o] = s2; }
    }
}

// ---------------- attention: scores GEMM + online weighted softmax ----------------
#define TD  16     // td rows per block
#define TEC 256    // te chunk
#define KC  32     // k chunk
__global__ __launch_bounds__(256) void attn_kernel(
    const float* __restrict__ enc_states,  // [B][T][H]
    const float* __restrict__ dec_hs,      // [B][T][H]
    const float* __restrict__ ew, const float* __restrict__ hw,
    const float* __restrict__ lin_b,
    float* __restrict__ out)               // [B][T]
{
    const int b   = blockIdx.y;
    const int td0 = blockIdx.x * TD;
    const int tid = threadIdx.x;
    const int tdt = tid >> 5;   // 0..7
    const int tet = tid & 31;   // 0..31

    __shared__ float Hx[HD][TD + 1];     // [k][td], pad to break staging conflicts
    __shared__ float E[KC][TEC];         // [k][te]

    // stage Hx for the whole k range once: thread -> (td = tid>>4, k16 = (tid&15)*16)
    {
        const int td  = tid >> 4;
        const int k16 = (tid & 15) * 16;
        const float* src = dec_hs + ((size_t)b * TT + td0 + td) * HD + k16;
        #pragma unroll
        for (int q = 0; q < 4; ++q) {
            float4 v = ((const float4*)(src + q * 4))[0];
            Hx[k16 + q * 4 + 0][td] = v.x;
            Hx[k16 + q * 4 + 1][td] = v.y;
            Hx[k16 + q * 4 + 2][td] = v.z;
            Hx[k16 + q * 4 + 3][td] = v.w;
        }
    }

    float M[2]  = {-1e30f, -1e30f};
    float Nm[2] = {0.f, 0.f};
    float Dn[2] = {0.f, 0.f};

    for (int tc = 0; tc < TT / TEC; ++tc) {
        const int te0 = tc * TEC;
        float S[2][8] = {{0.f}};
        for (int kc = 0; kc < HD / KC; ++kc) {
            const int k0 = kc * KC;
            __syncthreads();
            // stage E chunk: thread = te row, 32 consecutive k as 8 float4
            {
                const float* src = enc_states + ((size_t)b * TT + te0 + tid) * HD + k0;
                #pragma unroll
                for (int q = 0; q < 8; ++q) {
                    float4 v = ((const float4*)(src + q * 4))[0];
                    E[q * 4 + 0][tid] = v.x;
                    E[q * 4 + 1][tid] = v.y;
                    E[q * 4 + 2][tid] = v.z;
                    E[q * 4 + 3][tid] = v.w;
                }
            }
            __syncthreads();
            #pragma unroll
            for (int k = 0; k < KC; ++k) {
                const float a0 = Hx[k0 + k][tdt * 2 + 0];
                const float a1 = Hx[k0 + k][tdt * 2 + 1];
                #pragma unroll
                for (int i = 0; i < 8; ++i) {
                    const float e = E[k][tet + 32 * i];
                    S[0][i] = fmaf(a0, e, S[0][i]);
                    S[1][i] = fmaf(a1, e, S[1][i]);
                }
            }
        }
        // online fold for this te chunk
        float ewv[8];
        #pragma unroll
        for (int i = 0; i < 8; ++i) ewv[i] = ew[(size_t)b * TT + te0 + tet + 32 * i];
        #pragma unroll
        for (int r = 0; r < 2; ++r) {
            float cm = S[r][0];
            #pragma unroll
            for (int i = 1; i < 8; ++i) cm = fmaxf(cm, S[r][i]);
            #pragma unroll
            for (int m = 1; m < 32; m <<= 1) cm = fmaxf(cm, __shfl_xor(cm, m));
            const float newM  = fmaxf(M[r], cm);
            const float scale = __expf(M[r] - newM);
            float nl = 0.f, dl = 0.f;
            #pragma unroll
            for (int i = 0; i < 8; ++i) {
                const float p = __expf(S[r][i] - newM);
                dl += p;
                nl = fmaf(p, ewv[i], nl);
            }
            #pragma unroll
            for (int m = 1; m < 32; m <<= 1) {
                nl += __shfl_xor(nl, m);
                dl += __shfl_xor(dl, m);
            }
            Nm[r] = Nm[r] * scale + nl;
            Dn[r] = Dn[r] * scale + dl;
            M[r]  = newM;
        }
    }

    if (tet == 0) {
        const float lb = lin_b[0];
        #pragma unroll
        for (int r = 0; r < 2; ++r) {
            const int td = td0 + tdt * 2 + r;
            out[(size_t)b * TT + td] = Nm[r] / Dn[r] + hw[(size_t)b * TT + td] + lb;
        }
    }
}

extern "C" void kernel_launch(void* const* d_in, const int* in_sizes, int n_in,
                              void* d_out, int out_size, void* d_ws, size_t ws_size,
                              hipStream_t stream)
{
    const float* x    = (const float*)d_in[0];
    const float* eWih = (const float*)d_in[1];
    const float* eWhh = (const float*)d_in[2];
    const float* ebih = (const float*)d_in[3];
    const float* ebhh = (const float*)d_in[4];
    const float* dWih = (const float*)d_in[5];
    const float* dWhh = (const float*)d_in[6];
    const float* dbih = (const float*)d_in[7];
    const float* dbhh = (const float*)d_in[8];
    const float* linW = (const float*)d_in[9];
    const float* linb = (const float*)d_in[10];
    float* out = (float*)d_out;

    float* p = (float*)d_ws;
    float* WTe = p;        p += (size_t)GD * HD;
    float* WTd = p;        p += (size_t)GD * HD;
    float* be  = p;        p += GD;
    float* bd  = p;        p += GD;
    float* h_last = p;     p += (size_t)BB * HD;
    float* enc_states = p; p += (size_t)BB * TT * HD;
    float* dec_hs = p;     p += (size_t)BB * TT * HD;
    float* ew = p;         p += (size_t)BB * TT;
    float* hw = p;         p += (size_t)BB * TT;

    prep_kernel<<<(GD * HD + 255) / 256, 256, 0, stream>>>(
        eWhh, ebih, ebhh, dWhh, dbih, dbhh, WTe, WTd, be, bd);
    lstm_scan_kernel<<<BB, 1024, 0, stream>>>(x, eWih, be, WTe, nullptr, enc_states, h_last);
    lstm_scan_kernel<<<BB, 1024, 0, stream>>>(x, dWih, bd, WTd, h_last, dec_hs, nullptr);
    proj_kernel<<<256, 256, 0, stream>>>(enc_states, dec_hs, linW, ew, hw);
    attn_kernel<<<dim3(TT / TD, BB), 256, 0, stream>>>(enc_states, dec_hs, ew, hw, linb, out);
}

// Round 2
// 17078.351 us; speedup vs baseline: 1.0824x; 1.0824x over previous
//
// Encoder-decoder LSTM + dot attention + linear, MI355X fp32.  R2
// Scan redesign: 4 blocks per batch chain (grid=256, cooperative launch),
// Whh register-resident (64 floats/thread), per-step cross-block h exchange
// via agent-scope atomics + per-(b,t) flag counters (zeroed in prep).
//  - decoder LSTM state is independent of attention -> scan then batch attention
//  - out = softmax(S)·ew + hx·w2 + b  where ew[b][te]=E[b,te]·w1  (ctx GEMM collapsed)
#include <hip/hip_runtime.h>
#include <math.h>

#define HD 256
#define GD 1024   // 4*H
#define TT 1024
#define BB 64

__device__ __forceinline__ float sig_(float x)  { return 1.f / (1.f + __expf(-x)); }
__device__ __forceinline__ float tanh_(float x) { return 1.f - 2.f / (1.f + __expf(2.f * x)); }

// ---------------- prep: transpose Whh -> [k][j], bias sums, zero flags ----------------
__global__ __launch_bounds__(256) void prep_kernel(
    const float* __restrict__ eW, const float* __restrict__ eb1, const float* __restrict__ eb2,
    const float* __restrict__ dW, const float* __restrict__ db1, const float* __restrict__ db2,
    float* __restrict__ WTe, float* __restrict__ WTd,
    float* __restrict__ be, float* __restrict__ bd,
    int* __restrict__ cnt_all)   // [2*B*T]
{
    int idx = blockIdx.x * 256 + threadIdx.x;
    if (idx < GD * HD) {
        int j = idx / HD, k = idx % HD;      // Whh[j][k]
        WTe[k * GD + j] = eW[idx];
        WTd[k * GD + j] = dW[idx];
    }
    if (idx < GD) {
        be[idx] = eb1[idx] + eb2[idx];
        bd[idx] = db1[idx] + db2[idx];
    }
    if (idx < 2 * BB * TT) cnt_all[idx] = 0;
}

// ---------------- LSTM scan: 4 blocks per chain, weights in VGPRs ----------------
// block = (b = blockIdx&63, q = blockIdx>>6); q owns hidden slice [64q,64q+64)
// thread: s = tid>>8 (k-quarter), gl = tid&255 (gate_type = gl>>6, kk = gl&63)
__global__ __launch_bounds__(1024) void lstm_scan_coop(
    const float* __restrict__ x,       // [B,T]
    const float* __restrict__ Wih,     // [4H]
    const float* __restrict__ bias,    // [4H] (bih+bhh)
    const float* __restrict__ WT,      // [H][4H]
    const float* __restrict__ h_init,  // nullptr, or enc_states base (reads [b][T-1][k])
    float* __restrict__ states,        // [B,T,H]
    int* __restrict__ cnt)             // [B*T] zeroed flags
{
    const int b   = blockIdx.x & 63;
    const int q   = blockIdx.x >> 6;
    const int tid = threadIdx.x;
    const int s   = tid >> 8;
    const int gl  = tid & 255;
    const int gate_type = gl >> 6;
    const int kk  = gl & 63;
    const int j   = gate_type * 256 + q * 64 + kk;   // global gate row

    __shared__ float h_lds[HD];
    __shared__ float red[1024];
    __shared__ float act[256];

    // ---- load this thread's 64 weight columns into VGPRs (once) ----
    float4 w4[16];
    {
        const float* wp = WT + (size_t)(s * 64) * GD + j;
        #pragma unroll
        for (int i = 0; i < 16; ++i) {
            float a0 = wp[(size_t)(4 * i + 0) * GD];
            float a1 = wp[(size_t)(4 * i + 1) * GD];
            float a2 = wp[(size_t)(4 * i + 2) * GD];
            float a3 = wp[(size_t)(4 * i + 3) * GD];
            w4[i] = make_float4(a0, a1, a2, a3);
        }
    }
    const float wih = Wih[j];
    const float bj  = bias[j];

    if (tid < HD) {
        h_lds[tid] = h_init ? h_init[((size_t)b * TT + (TT - 1)) * HD + tid] : 0.f;
    }
    float c = 0.f;   // live in threads tid<64 only
    __syncthreads();

    const int bt0 = b * TT;
    for (int t = 0; t < TT; ++t) {
        // ---- gate pre-activation partial: 64 FMAs, h broadcast from LDS ----
        const float xt = x[bt0 + t];
        float acc = (s == 0) ? fmaf(xt, wih, bj) : 0.f;
        const float4* h4 = (const float4*)(h_lds + s * 64);
        #pragma unroll
        for (int i = 0; i < 16; ++i) {
            float4 hv = h4[i];
            acc = fmaf(hv.x, w4[i].x, acc);
            acc = fmaf(hv.y, w4[i].y, acc);
            acc = fmaf(hv.z, w4[i].z, acc);
            acc = fmaf(hv.w, w4[i].w, acc);
        }
        red[tid] = acc;
        __syncthreads();                                  // (1)

        if (tid < 256) {
            float v = red[tid] + red[tid + 256] + red[tid + 512] + red[tid + 768];
            act[tid] = (gate_type == 2) ? tanh_(v) : sig_(v);
        }
        __syncthreads();                                  // (2)

        float* dst = states + ((size_t)(bt0 + t)) * HD;
        if (tid < 64) {
            float gi = act[tid], gf = act[64 + tid], gg = act[128 + tid], go = act[192 + tid];
            c = fmaf(gf, c, gi * gg);
            float h = go * tanh_(c);
            __hip_atomic_store(dst + q * 64 + tid, h, __ATOMIC_RELAXED, __HIP_MEMORY_SCOPE_AGENT);
        }
        // wave 0 lanes 0..63 issued the stores; tid 0 (same wave, program order) releases
        if (tid == 0) {
            __threadfence();
            __hip_atomic_fetch_add(&cnt[bt0 + t], 1, __ATOMIC_RELEASE, __HIP_MEMORY_SCOPE_AGENT);
            while (__hip_atomic_load(&cnt[bt0 + t], __ATOMIC_ACQUIRE, __HIP_MEMORY_SCOPE_AGENT) < 4) {}
        }
        __syncthreads();                                  // (3) all slices published
        if (tid < HD)
            h_lds[tid] = __hip_atomic_load(dst + tid, __ATOMIC_RELAXED, __HIP_MEMORY_SCOPE_AGENT);
        __syncthreads();                                  // (4)
    }
}

// ---------------- proj: ew[b][t]=E·w1, hw[b][t]=Hx·w2 (one wave per row) ----------------
__global__ __launch_bounds__(256) void proj_kernel(
    const float* __restrict__ enc_states, const float* __restrict__ dec_hs,
    const float* __restrict__ linW, float* __restrict__ ew, float* __restrict__ hw)
{
    const int lane = threadIdx.x & 63;
    const int wid  = blockIdx.x * 4 + (threadIdx.x >> 6);
    const int nw   = gridDim.x * 4;
    const float4 w1 = ((const float4*)linW)[lane];
    const float4 w2 = ((const float4*)(linW + HD))[lane];
    for (int o = wid; o < BB * TT; o += nw) {
        float4 v1 = ((const float4*)(enc_states + (size_t)o * HD))[lane];
        float4 v2 = ((const float4*)(dec_hs     + (size_t)o * HD))[lane];
        float s1 = v1.x * w1.x + v1.y * w1.y + v1.z * w1.z + v1.w * w1.w;
        float s2 = v2.x * w2.x + v2.y * w2.y + v2.z * w2.z + v2.w * w2.w;
        #pragma unroll
        for (int m = 1; m < 64; m <<= 1) {
            s1 += __shfl_xor(s1, m);
            s2 += __shfl_xor(s2, m);
        }
        if (lane == 0) { ew[o] = s1; hw[o] = s2; }
    }
}

// ---------------- attention: scores GEMM + online weighted softmax ----------------
#define TD  16     // td rows per block
#define TEC 256    // te chunk
#define KC  32     // k chunk
__global__ __launch_bounds__(256) void attn_kernel(
    const float* __restrict__ enc_states,  // [B][T][H]
    const float* __restrict__ dec_hs,      // [B][T][H]
    const float* __restrict__ ew, const float* __restrict__ hw,
    const float* __restrict__ lin_b,
    float* __restrict__ out)               // [B][T]
{
    const int b   = blockIdx.y;
    const int td0 = blockIdx.x * TD;
    const int tid = threadIdx.x;
    const int tdt = tid >> 5;   // 0..7
    const int tet = tid & 31;   // 0..31

    __shared__ float Hx[HD][TD + 1];     // [k][td]
    __shared__ float E[KC][TEC];         // [k][te]

    // stage Hx for the whole k range once: thread -> (td = tid>>4, k16 = (tid&15)*16)
    {
        const int td  = tid >> 4;
        const int k16 = (tid & 15) * 16;
        const float* src = dec_hs + ((size_t)b * TT + td0 + td) * HD + k16;
        #pragma unroll
        for (int q = 0; q < 4; ++q) {
            float4 v = ((const float4*)(src + q * 4))[0];
            Hx[k16 + q * 4 + 0][td] = v.x;
            Hx[k16 + q * 4 + 1][td] = v.y;
            Hx[k16 + q * 4 + 2][td] = v.z;
            Hx[k16 + q * 4 + 3][td] = v.w;
        }
    }

    float M[2]  = {-1e30f, -1e30f};
    float Nm[2] = {0.f, 0.f};
    float Dn[2] = {0.f, 0.f};

    for (int tc = 0; tc < TT / TEC; ++tc) {
        const int te0 = tc * TEC;
        float S[2][8] = {{0.f}};
        for (int kc = 0; kc < HD / KC; ++kc) {
            const int k0 = kc * KC;
            __syncthreads();
            {
                const float* src = enc_states + ((size_t)b * TT + te0 + tid) * HD + k0;
                #pragma unroll
                for (int qq = 0; qq < 8; ++qq) {
                    float4 v = ((const float4*)(src + qq * 4))[0];
                    E[qq * 4 + 0][tid] = v.x;
                    E[qq * 4 + 1][tid] = v.y;
                    E[qq * 4 + 2][tid] = v.z;
                    E[qq * 4 + 3][tid] = v.w;
                }
            }
            __syncthreads();
            #pragma unroll
            for (int k = 0; k < KC; ++k) {
                const float a0 = Hx[k0 + k][tdt * 2 + 0];
                const float a1 = Hx[k0 + k][tdt * 2 + 1];
                #pragma unroll
                for (int i = 0; i < 8; ++i) {
                    const float e = E[k][tet + 32 * i];
                    S[0][i] = fmaf(a0, e, S[0][i]);
                    S[1][i] = fmaf(a1, e, S[1][i]);
                }
            }
        }
        float ewv[8];
        #pragma unroll
        for (int i = 0; i < 8; ++i) ewv[i] = ew[(size_t)b * TT + te0 + tet + 32 * i];
        #pragma unroll
        for (int r = 0; r < 2; ++r) {
            float cm = S[r][0];
            #pragma unroll
            for (int i = 1; i < 8; ++i) cm = fmaxf(cm, S[r][i]);
            #pragma unroll
            for (int m = 1; m < 32; m <<= 1) cm = fmaxf(cm, __shfl_xor(cm, m));
            const float newM  = fmaxf(M[r], cm);
            const float scale = __expf(M[r] - newM);
            float nl = 0.f, dl = 0.f;
            #pragma unroll
            for (int i = 0; i < 8; ++i) {
                const float p = __expf(S[r][i] - newM);
                dl += p;
                nl = fmaf(p, ewv[i], nl);
            }
            #pragma unroll
            for (int m = 1; m < 32; m <<= 1) {
                nl += __shfl_xor(nl, m);
                dl += __shfl_xor(dl, m);
            }
            Nm[r] = Nm[r] * scale + nl;
            Dn[r] = Dn[r] * scale + dl;
            M[r]  = newM;
        }
    }

    if (tet == 0) {
        const float lb = lin_b[0];
        #pragma unroll
        for (int r = 0; r < 2; ++r) {
            const int td = td0 + tdt * 2 + r;
            out[(size_t)b * TT + td] = Nm[r] / Dn[r] + hw[(size_t)b * TT + td] + lb;
        }
    }
}

extern "C" void kernel_launch(void* const* d_in, const int* in_sizes, int n_in,
                              void* d_out, int out_size, void* d_ws, size_t ws_size,
                              hipStream_t stream)
{
    const float* x    = (const float*)d_in[0];
    const float* eWih = (const float*)d_in[1];
    const float* eWhh = (const float*)d_in[2];
    const float* ebih = (const float*)d_in[3];
    const float* ebhh = (const float*)d_in[4];
    const float* dWih = (const float*)d_in[5];
    const float* dWhh = (const float*)d_in[6];
    const float* dbih = (const float*)d_in[7];
    const float* dbhh = (const float*)d_in[8];
    const float* linW = (const float*)d_in[9];
    const float* linb = (const float*)d_in[10];
    float* out = (float*)d_out;

    float* p = (float*)d_ws;
    float* WTe = p;        p += (size_t)GD * HD;
    float* WTd = p;        p += (size_t)GD * HD;
    float* be  = p;        p += GD;
    float* bd  = p;        p += GD;
    float* enc_states = p; p += (size_t)BB * TT * HD;
    float* dec_hs = p;     p += (size_t)BB * TT * HD;
    float* ew = p;         p += (size_t)BB * TT;
    float* hw = p;         p += (size_t)BB * TT;
    int* cnt_e = (int*)p;  p += (size_t)BB * TT;   // int flags in float-sized slots
    int* cnt_d = (int*)p;  p += (size_t)BB * TT;

    prep_kernel<<<(GD * HD + 255) / 256, 256, 0, stream>>>(
        eWhh, ebih, ebhh, dWhh, dbih, dbhh, WTe, WTd, be, bd, cnt_e);

    {
        const float* hi = nullptr;
        void* args[] = {(void*)&x, (void*)&eWih, (void*)&be, (void*)&WTe,
                        (void*)&hi, (void*)&enc_states, (void*)&cnt_e};
        hipLaunchCooperativeKernel((void*)lstm_scan_coop, dim3(256), dim3(1024),
                                   args, 0, stream);
    }
    {
        const float* hi = enc_states;
        void* args[] = {(void*)&x, (void*)&dWih, (void*)&bd, (void*)&WTd,
                        (void*)&hi, (void*)&dec_hs, (void*)&cnt_d};
        hipLaunchCooperativeKernel((void*)lstm_scan_coop, dim3(256), dim3(1024),
                                   args, 0, stream);
    }

    proj_kernel<<<256, 256, 0, stream>>>(enc_states, dec_hs, linW, ew, hw);
    attn_kernel<<<dim3(TT / TD, BB), 256, 0, stream>>>(enc_states, dec_hs, ew, hw, linb, out);
}

// Round 3
// 4240.308 us; speedup vs baseline: 4.3597x; 4.0276x over previous
//
// Encoder-decoder LSTM + dot attention + linear, MI355X fp32.  R3
// Scan: 4 blocks/chain (grid=256 coop), Whh register-resident (128 f32/thread),
// cross-block h exchange via FENCE-FREE tagged 8B relaxed agent atomics
// ({f32 h, u32 tag} travels together; double-buffered by t&1; no flags/fences).
// R2 post-mortem: acquire/release agent fences (wbl2/inv per step) cost 7.9us/step.
//  - decoder LSTM state is independent of attention -> scan then batch attention
//  - out = softmax(S)·ew + hx·w2 + b  where ew[b][te]=E[b,te]·w1 (ctx GEMM collapsed)
#include <hip/hip_runtime.h>
#include <math.h>

#define HD 256
#define GD 1024   // 4*H
#define TT 1024
#define BB 64
#define NT 512    // scan block size

__device__ __forceinline__ float sig_(float x)  { return 1.f / (1.f + __expf(-x)); }
__device__ __forceinline__ float tanh_(float x) { return 1.f - 2.f / (1.f + __expf(2.f * x)); }

// ---------------- prep: transpose Whh -> [k][j], bias sums, zero exchange ----------------
__global__ __launch_bounds__(256) void prep_kernel(
    const float* __restrict__ eW, const float* __restrict__ eb1, const float* __restrict__ eb2,
    const float* __restrict__ dW, const float* __restrict__ db1, const float* __restrict__ db2,
    float* __restrict__ WTe, float* __restrict__ WTd,
    float* __restrict__ be, float* __restrict__ bd,
    unsigned long long* __restrict__ ex_all)   // [2 scans][B][2][256]
{
    int idx = blockIdx.x * 256 + threadIdx.x;
    if (idx < GD * HD) {
        int j = idx / HD, k = idx % HD;      // Whh[j][k]
        WTe[k * GD + j] = eW[idx];
        WTd[k * GD + j] = dW[idx];
    }
    if (idx < GD) {
        be[idx] = eb1[idx] + eb2[idx];
        bd[idx] = db1[idx] + db2[idx];
    }
    if (idx < 2 * BB * 2 * 256) ex_all[idx] = 0ULL;   // tags=0 (< any t+1)
}

// ---------------- LSTM scan: 4 blocks/chain, weights in VGPRs, tagged exchange ----------
// block = (b = blk&63, q = blk>>6); q owns hidden dims [64q, 64q+64)
// thread: s = tid&3 (k-quarter), jj = tid>>2 (row-pair 2jj,2jj+1 of block's 256 gate rows)
__global__ __launch_bounds__(NT, 2) void lstm_scan_coop(
    const float* __restrict__ x,       // [B,T]
    const float* __restrict__ Wih,     // [4H]
    const float* __restrict__ bias,    // [4H] (bih+bhh)
    const float* __restrict__ WT,      // [H][4H]
    const float* __restrict__ h_init,  // nullptr, or enc_states (reads [b][T-1][:])
    float* __restrict__ states,        // [B,T,H]
    unsigned long long* __restrict__ ex)  // [B][2][256] tagged slots
{
    const int b   = blockIdx.x & 63;
    const int q   = blockIdx.x >> 6;
    const int tid = threadIdx.x;
    const int s   = tid & 3;            // k-quarter
    const int jj  = tid >> 2;           // 0..127
    const int gate = jj >> 5;           // 0:i 1:f 2:g 3:o
    const int kk0  = (jj & 31) * 2;     // local dim pair
    const int r0   = gate * 64 + kk0;   // local row in [0,256)
    const int jg0  = gate * 256 + q * 64 + kk0;  // global gate row

    // replica s holds h[64s..64s+64); 264-stride => quarter bases 8 banks apart
    __shared__ float h_rep[4][264];
    __shared__ float act_s[256];
    __shared__ float x_s[TT];

    // ---- weights for rows jg0, jg0+1 over k in [64s,64s+64): 128 VGPRs ----
    float4 w0[16], w1[16];
    {
        const float* basek = WT + (size_t)(s * 64) * GD;
        #pragma unroll
        for (int i = 0; i < 16; ++i) {
            const float* p0 = basek + (size_t)(4 * i) * GD + jg0;
            w0[i] = make_float4(p0[0], p0[GD], p0[2 * GD], p0[3 * GD]);
            const float* p1 = p0 + 1;
            w1[i] = make_float4(p1[0], p1[GD], p1[2 * GD], p1[3 * GD]);
        }
    }
    const float wih0 = Wih[jg0], wih1 = Wih[jg0 + 1];
    const float bj0  = bias[jg0], bj1  = bias[jg0 + 1];

    for (int i = tid; i < TT; i += NT) x_s[i] = x[b * TT + i];
    if (tid < 256) {
        float hv = h_init ? h_init[((size_t)b * TT + (TT - 1)) * HD + tid] : 0.f;
        h_rep[tid >> 6][tid & 63] = hv;
    }
    float c = 0.f;   // live in wave q (tid in [64q,64q+64)) only
    __syncthreads();

    for (int t = 0; t < TT; ++t) {
        // ---- gate pre-activation partial over this thread's k-quarter ----
        const float xt = x_s[t];
        float a0, a1;
        if (s == 0) { a0 = fmaf(xt, wih0, bj0); a1 = fmaf(xt, wih1, bj1); }
        else        { a0 = 0.f;                 a1 = 0.f; }
        const float4* h4 = (const float4*)(&h_rep[s][0]);
        #pragma unroll
        for (int i = 0; i < 16; ++i) {
            float4 hv = h4[i];
            a0 = fmaf(hv.x, w0[i].x, a0); a0 = fmaf(hv.y, w0[i].y, a0);
            a0 = fmaf(hv.z, w0[i].z, a0); a0 = fmaf(hv.w, w0[i].w, a0);
            a1 = fmaf(hv.x, w1[i].x, a1); a1 = fmaf(hv.y, w1[i].y, a1);
            a1 = fmaf(hv.z, w1[i].z, a1); a1 = fmaf(hv.w, w1[i].w, a1);
        }
        // reduce 4 k-quarter partials: lanes 4jj+{0,1,2,3}
        a0 += __shfl_xor(a0, 1); a0 += __shfl_xor(a0, 2);
        a1 += __shfl_xor(a1, 1); a1 += __shfl_xor(a1, 2);
        if (s == 0) {
            float2 av;
            av.x = (gate == 2) ? tanh_(a0) : sig_(a0);
            av.y = (gate == 2) ? tanh_(a1) : sig_(a1);
            *(float2*)(&act_s[r0]) = av;
        }
        __syncthreads();   // act ready

        unsigned long long* slot = ex + ((size_t)b * 2 + (t & 1)) * 256;
        if (tid < 256) {
            const int dq = tid >> 6, dk = tid & 63;
            if (dq == q) {
                // wave q: c/h update + publish own slice
                float gi = act_s[dk], gf = act_s[64 + dk], gg = act_s[128 + dk], go = act_s[192 + dk];
                c = fmaf(gf, c, gi * gg);
                float h = go * tanh_(c);
                h_rep[q][dk] = h;
                states[((size_t)(b * TT + t)) * HD + tid] = h;
                unsigned long long pk = ((unsigned long long)(unsigned)(t + 1) << 32)
                                      | (unsigned long long)__float_as_uint(h);
                __hip_atomic_store(&slot[tid], pk, __ATOMIC_RELAXED, __HIP_MEMORY_SCOPE_AGENT);
            } else {
                // poll remote dim: tag carries validity, no fences needed
                unsigned long long u;
                do {
                    u = __hip_atomic_load(&slot[tid], __ATOMIC_RELAXED, __HIP_MEMORY_SCOPE_AGENT);
                } while ((unsigned)(u >> 32) != (unsigned)(t + 1));
                h_rep[dq][dk] = __uint_as_float((unsigned)u);
            }
        }
        __syncthreads();   // h replicas ready for t+1
    }
}

// ---------------- proj: ew[b][t]=E·w1, hw[b][t]=Hx·w2 (one wave per row) ----------------
__global__ __launch_bounds__(256) void proj_kernel(
    const float* __restrict__ enc_states, const float* __restrict__ dec_hs,
    const float* __restrict__ linW, float* __restrict__ ew, float* __restrict__ hw)
{
    const int lane = threadIdx.x & 63;
    const int wid  = blockIdx.x * 4 + (threadIdx.x >> 6);
    const int nw   = gridDim.x * 4;
    const float4 w1 = ((const float4*)linW)[lane];
    const float4 w2 = ((const float4*)(linW + HD))[lane];
    for (int o = wid; o < BB * TT; o += nw) {
        float4 v1 = ((const float4*)(enc_states + (size_t)o * HD))[lane];
        float4 v2 = ((const float4*)(dec_hs     + (size_t)o * HD))[lane];
        float s1 = v1.x * w1.x + v1.y * w1.y + v1.z * w1.z + v1.w * w1.w;
        float s2 = v2.x * w2.x + v2.y * w2.y + v2.z * w2.z + v2.w * w2.w;
        #pragma unroll
        for (int m = 1; m < 64; m <<= 1) {
            s1 += __shfl_xor(s1, m);
            s2 += __shfl_xor(s2, m);
        }
        if (lane == 0) { ew[o] = s1; hw[o] = s2; }
    }
}

// ---------------- attention: scores GEMM + online weighted softmax ----------------
#define TD  16     // td rows per block
#define TEC 256    // te chunk
#define KC  32     // k chunk
__global__ __launch_bounds__(256) void attn_kernel(
    const float* __restrict__ enc_states,  // [B][T][H]
    const float* __restrict__ dec_hs,      // [B][T][H]
    const float* __restrict__ ew, const float* __restrict__ hw,
    const float* __restrict__ lin_b,
    float* __restrict__ out)               // [B][T]
{
    const int b   = blockIdx.y;
    const int td0 = blockIdx.x * TD;
    const int tid = threadIdx.x;
    const int tdt = tid >> 5;   // 0..7
    const int tet = tid & 31;   // 0..31

    __shared__ float Hx[HD][TD + 1];
    __shared__ float E[KC][TEC];

    {
        const int td  = tid >> 4;
        const int k16 = (tid & 15) * 16;
        const float* src = dec_hs + ((size_t)b * TT + td0 + td) * HD + k16;
        #pragma unroll
        for (int qq = 0; qq < 4; ++qq) {
            float4 v = ((const float4*)(src + qq * 4))[0];
            Hx[k16 + qq * 4 + 0][td] = v.x;
            Hx[k16 + qq * 4 + 1][td] = v.y;
            Hx[k16 + qq * 4 + 2][td] = v.z;
            Hx[k16 + qq * 4 + 3][td] = v.w;
        }
    }

    float M[2]  = {-1e30f, -1e30f};
    float Nm[2] = {0.f, 0.f};
    float Dn[2] = {0.f, 0.f};

    for (int tc = 0; tc < TT / TEC; ++tc) {
        const int te0 = tc * TEC;
        float S[2][8] = {{0.f}};
        for (int kc = 0; kc < HD / KC; ++kc) {
            const int k0 = kc * KC;
            __syncthreads();
            {
                const float* src = enc_states + ((size_t)b * TT + te0 + tid) * HD + k0;
                #pragma unroll
                for (int qq = 0; qq < 8; ++qq) {
                    float4 v = ((const float4*)(src + qq * 4))[0];
                    E[qq * 4 + 0][tid] = v.x;
                    E[qq * 4 + 1][tid] = v.y;
                    E[qq * 4 + 2][tid] = v.z;
                    E[qq * 4 + 3][tid] = v.w;
                }
            }
            __syncthreads();
            #pragma unroll
            for (int k = 0; k < KC; ++k) {
                const float a0 = Hx[k0 + k][tdt * 2 + 0];
                const float a1 = Hx[k0 + k][tdt * 2 + 1];
                #pragma unroll
                for (int i = 0; i < 8; ++i) {
                    const float e = E[k][tet + 32 * i];
                    S[0][i] = fmaf(a0, e, S[0][i]);
                    S[1][i] = fmaf(a1, e, S[1][i]);
                }
            }
        }
        float ewv[8];
        #pragma unroll
        for (int i = 0; i < 8; ++i) ewv[i] = ew[(size_t)b * TT + te0 + tet + 32 * i];
        #pragma unroll
        for (int r = 0; r < 2; ++r) {
            float cm = S[r][0];
            #pragma unroll
            for (int i = 1; i < 8; ++i) cm = fmaxf(cm, S[r][i]);
            #pragma unroll
            for (int m = 1; m < 32; m <<= 1) cm = fmaxf(cm, __shfl_xor(cm, m));
            const float newM  = fmaxf(M[r], cm);
            const float scale = __expf(M[r] - newM);
            float nl = 0.f, dl = 0.f;
            #pragma unroll
            for (int i = 0; i < 8; ++i) {
                const float p = __expf(S[r][i] - newM);
                dl += p;
                nl = fmaf(p, ewv[i], nl);
            }
            #pragma unroll
            for (int m = 1; m < 32; m <<= 1) {
                nl += __shfl_xor(nl, m);
                dl += __shfl_xor(dl, m);
            }
            Nm[r] = Nm[r] * scale + nl;
            Dn[r] = Dn[r] * scale + dl;
            M[r]  = newM;
        }
    }

    if (tet == 0) {
        const float lb = lin_b[0];
        #pragma unroll
        for (int r = 0; r < 2; ++r) {
            const int td = td0 + tdt * 2 + r;
            out[(size_t)b * TT + td] = Nm[r] / Dn[r] + hw[(size_t)b * TT + td] + lb;
        }
    }
}

extern "C" void kernel_launch(void* const* d_in, const int* in_sizes, int n_in,
                              void* d_out, int out_size, void* d_ws, size_t ws_size,
                              hipStream_t stream)
{
    const float* x    = (const float*)d_in[0];
    const float* eWih = (const float*)d_in[1];
    const float* eWhh = (const float*)d_in[2];
    const float* ebih = (const float*)d_in[3];
    const float* ebhh = (const float*)d_in[4];
    const float* dWih = (const float*)d_in[5];
    const float* dWhh = (const float*)d_in[6];
    const float* dbih = (const float*)d_in[7];
    const float* dbhh = (const float*)d_in[8];
    const float* linW = (const float*)d_in[9];
    const float* linb = (const float*)d_in[10];
    float* out = (float*)d_out;

    float* p = (float*)d_ws;
    float* WTe = p;        p += (size_t)GD * HD;
    float* WTd = p;        p += (size_t)GD * HD;
    float* be  = p;        p += GD;
    float* bd  = p;        p += GD;
    float* enc_states = p; p += (size_t)BB * TT * HD;
    float* dec_hs = p;     p += (size_t)BB * TT * HD;
    float* ew = p;         p += (size_t)BB * TT;
    float* hw = p;         p += (size_t)BB * TT;
    unsigned long long* ex_e = (unsigned long long*)p; p += (size_t)BB * 2 * 256 * 2;
    unsigned long long* ex_d = (unsigned long long*)p; p += (size_t)BB * 2 * 256 * 2;

    prep_kernel<<<(GD * HD + 255) / 256, 256, 0, stream>>>(
        eWhh, ebih, ebhh, dWhh, dbih, dbhh, WTe, WTd, be, bd, ex_e);

    {
        const float* hi = nullptr;
        void* args[] = {(void*)&x, (void*)&eWih, (void*)&be, (void*)&WTe,
                        (void*)&hi, (void*)&enc_states, (void*)&ex_e};
        hipLaunchCooperativeKernel((void*)lstm_scan_coop, dim3(256), dim3(NT),
                                   args, 0, stream);
    }
    {
        const float* hi = enc_states;
        void* args[] = {(void*)&x, (void*)&dWih, (void*)&bd, (void*)&WTd,
                        (void*)&hi, (void*)&dec_hs, (void*)&ex_d};
        hipLaunchCooperativeKernel((void*)lstm_scan_coop, dim3(256), dim3(NT),
                                   args, 0, stream);
    }

    proj_kernel<<<256, 256, 0, stream>>>(enc_states, dec_hs, linW, ew, hw);
    attn_kernel<<<dim3(TT / TD, BB), 256, 0, stream>>>(enc_states, dec_hs, ew, hw, linb, out);
}

// Round 4
// 3863.997 us; speedup vs baseline: 4.7843x; 1.0974x over previous
//
// Encoder-decoder LSTM + dot attention + linear, MI355X fp32.  R4
// R3 post-mortem: scans 1625us each (poll-RT-bound, 3800cyc/step), attn ~920us
// (LDS-issue-bound: 10 b32 reads per 16 FMAs). This round:
//  - attn v2: TD=32, 4x8 register tile, Hx[k][td] stride-36 -> one b128 (broadcast)
//    + 8 conflict-free b32 E reads per 32 FMAs => FMA-bound (~350us predicted)
//  - scan: split accumulators (shorter dep chain) + publish-first ordering
#include <hip/hip_runtime.h>
#include <math.h>

#define HD 256
#define GD 1024   // 4*H
#define TT 1024
#define BB 64
#define NT 512    // scan block size

__device__ __forceinline__ float sig_(float x)  { return 1.f / (1.f + __expf(-x)); }
__device__ __forceinline__ float tanh_(float x) { return 1.f - 2.f / (1.f + __expf(2.f * x)); }

// ---------------- prep: transpose Whh -> [k][j], bias sums, zero exchange ----------------
__global__ __launch_bounds__(256) void prep_kernel(
    const float* __restrict__ eW, const float* __restrict__ eb1, const float* __restrict__ eb2,
    const float* __restrict__ dW, const float* __restrict__ db1, const float* __restrict__ db2,
    float* __restrict__ WTe, float* __restrict__ WTd,
    float* __restrict__ be, float* __restrict__ bd,
    unsigned long long* __restrict__ ex_all)   // [2 scans][B][2][256]
{
    int idx = blockIdx.x * 256 + threadIdx.x;
    if (idx < GD * HD) {
        int j = idx / HD, k = idx % HD;      // Whh[j][k]
        WTe[k * GD + j] = eW[idx];
        WTd[k * GD + j] = dW[idx];
    }
    if (idx < GD) {
        be[idx] = eb1[idx] + eb2[idx];
        bd[idx] = db1[idx] + db2[idx];
    }
    if (idx < 2 * BB * 2 * 256) ex_all[idx] = 0ULL;   // tags=0 (< any t+1)
}

// ---------------- LSTM scan: 4 blocks/chain, weights in VGPRs, tagged exchange ----------
// block = (b = blk&63, q = blk>>6); q owns hidden dims [64q, 64q+64)
// thread: s = tid&3 (k-quarter), jj = tid>>2 (row-pair 2jj,2jj+1 of block's 256 gate rows)
__global__ __launch_bounds__(NT, 2) void lstm_scan_coop(
    const float* __restrict__ x,       // [B,T]
    const float* __restrict__ Wih,     // [4H]
    const float* __restrict__ bias,    // [4H] (bih+bhh)
    const float* __restrict__ WT,      // [H][4H]
    const float* __restrict__ h_init,  // nullptr, or enc_states (reads [b][T-1][:])
    float* __restrict__ states,        // [B,T,H]
    unsigned long long* __restrict__ ex)  // [B][2][256] tagged slots
{
    const int b   = blockIdx.x & 63;
    const int q   = blockIdx.x >> 6;
    const int tid = threadIdx.x;
    const int s   = tid & 3;            // k-quarter
    const int jj  = tid >> 2;           // 0..127
    const int gate = jj >> 5;           // 0:i 1:f 2:g 3:o
    const int kk0  = (jj & 31) * 2;     // local dim pair
    const int r0   = gate * 64 + kk0;   // local row in [0,256)
    const int jg0  = gate * 256 + q * 64 + kk0;  // global gate row

    __shared__ float h_rep[4][264];
    __shared__ float act_s[256];
    __shared__ float x_s[TT];

    // ---- weights for rows jg0, jg0+1 over k in [64s,64s+64): 128 VGPRs ----
    float4 w0[16], w1[16];
    {
        const float* basek = WT + (size_t)(s * 64) * GD;
        #pragma unroll
        for (int i = 0; i < 16; ++i) {
            const float* p0 = basek + (size_t)(4 * i) * GD + jg0;
            w0[i] = make_float4(p0[0], p0[GD], p0[2 * GD], p0[3 * GD]);
            const float* p1 = p0 + 1;
            w1[i] = make_float4(p1[0], p1[GD], p1[2 * GD], p1[3 * GD]);
        }
    }
    const float wih0 = Wih[jg0], wih1 = Wih[jg0 + 1];
    const float bj0  = bias[jg0], bj1  = bias[jg0 + 1];

    for (int i = tid; i < TT; i += NT) x_s[i] = x[b * TT + i];
    if (tid < 256) {
        float hv = h_init ? h_init[((size_t)b * TT + (TT - 1)) * HD + tid] : 0.f;
        h_rep[tid >> 6][tid & 63] = hv;
    }
    float c = 0.f;   // live in wave q (tid in [64q,64q+64)) only
    __syncthreads();

    for (int t = 0; t < TT; ++t) {
        // ---- gate pre-activation partial over this thread's k-quarter ----
        // split accumulators: halve the serial FMA dependency chain
        const float xt = x_s[t];
        float a0p, a1p, a0q = 0.f, a1q = 0.f;
        if (s == 0) { a0p = fmaf(xt, wih0, bj0); a1p = fmaf(xt, wih1, bj1); }
        else        { a0p = 0.f;                 a1p = 0.f; }
        const float4* h4 = (const float4*)(&h_rep[s][0]);
        #pragma unroll
        for (int i = 0; i < 8; ++i) {
            float4 hv = h4[i];
            a0p = fmaf(hv.x, w0[i].x, a0p); a0p = fmaf(hv.y, w0[i].y, a0p);
            a0p = fmaf(hv.z, w0[i].z, a0p); a0p = fmaf(hv.w, w0[i].w, a0p);
            a1p = fmaf(hv.x, w1[i].x, a1p); a1p = fmaf(hv.y, w1[i].y, a1p);
            a1p = fmaf(hv.z, w1[i].z, a1p); a1p = fmaf(hv.w, w1[i].w, a1p);
        }
        #pragma unroll
        for (int i = 8; i < 16; ++i) {
            float4 hv = h4[i];
            a0q = fmaf(hv.x, w0[i].x, a0q); a0q = fmaf(hv.y, w0[i].y, a0q);
            a0q = fmaf(hv.z, w0[i].z, a0q); a0q = fmaf(hv.w, w0[i].w, a0q);
            a1q = fmaf(hv.x, w1[i].x, a1q); a1q = fmaf(hv.y, w1[i].y, a1q);
            a1q = fmaf(hv.z, w1[i].z, a1q); a1q = fmaf(hv.w, w1[i].w, a1q);
        }
        float a0 = a0p + a0q;
        float a1 = a1p + a1q;
        a0 += __shfl_xor(a0, 1); a0 += __shfl_xor(a0, 2);
        a1 += __shfl_xor(a1, 1); a1 += __shfl_xor(a1, 2);
        if (s == 0) {
            float2 av;
            av.x = (gate == 2) ? tanh_(a0) : sig_(a0);
            av.y = (gate == 2) ? tanh_(a1) : sig_(a1);
            *(float2*)(&act_s[r0]) = av;
        }
        __syncthreads();   // act ready

        unsigned long long* slot = ex + ((size_t)b * 2 + (t & 1)) * 256;
        if (tid < 256) {
            const int dq = tid >> 6, dk = tid & 63;
            if (dq == q) {
                float gi = act_s[dk], gf = act_s[64 + dk], gg = act_s[128 + dk], go = act_s[192 + dk];
                c = fmaf(gf, c, gi * gg);
                float h = go * tanh_(c);
                // publish FIRST: visibility to remote pollers starts earliest
                unsigned long long pk = ((unsigned long long)(unsigned)(t + 1) << 32)
                                      | (unsigned long long)__float_as_uint(h);
                __hip_atomic_store(&slot[tid], pk, __ATOMIC_RELAXED, __HIP_MEMORY_SCOPE_AGENT);
                h_rep[q][dk] = h;
                states[((size_t)(b * TT + t)) * HD + tid] = h;
            } else {
                unsigned long long u;
                do {
                    u = __hip_atomic_load(&slot[tid], __ATOMIC_RELAXED, __HIP_MEMORY_SCOPE_AGENT);
                } while ((unsigned)(u >> 32) != (unsigned)(t + 1));
                h_rep[dq][dk] = __uint_as_float((unsigned)u);
            }
        }
        __syncthreads();   // h replicas ready for t+1
    }
}

// ---------------- proj: ew[b][t]=E·w1, hw[b][t]=Hx·w2 (one wave per row) ----------------
__global__ __launch_bounds__(256) void proj_kernel(
    const float* __restrict__ enc_states, const float* __restrict__ dec_hs,
    const float* __restrict__ linW, float* __restrict__ ew, float* __restrict__ hw)
{
    const int lane = threadIdx.x & 63;
    const int wid  = blockIdx.x * 4 + (threadIdx.x >> 6);
    const int nw   = gridDim.x * 4;
    const float4 w1 = ((const float4*)linW)[lane];
    const float4 w2 = ((const float4*)(linW + HD))[lane];
    for (int o = wid; o < BB * TT; o += nw) {
        float4 v1 = ((const float4*)(enc_states + (size_t)o * HD))[lane];
        float4 v2 = ((const float4*)(dec_hs     + (size_t)o * HD))[lane];
        float s1 = v1.x * w1.x + v1.y * w1.y + v1.z * w1.z + v1.w * w1.w;
        float s2 = v2.x * w2.x + v2.y * w2.y + v2.z * w2.z + v2.w * w2.w;
        #pragma unroll
        for (int m = 1; m < 64; m <<= 1) {
            s1 += __shfl_xor(s1, m);
            s2 += __shfl_xor(s2, m);
        }
        if (lane == 0) { ew[o] = s1; hw[o] = s2; }
    }
}

// ---------------- attention v2: 32 td rows/block, 4x8 register tile ----------------
// Hx[k][td] stride 36 (16B-aligned rows): per k one wave-uniform ds_read_b128
// E[k][te]: lane-consecutive b32 reads (conflict-free, broadcast across td groups)
#define TD2  32    // td rows per block
#define TEC2 256   // te chunk
#define KC2  32    // k chunk
__global__ __launch_bounds__(256) void attn_kernel(
    const float* __restrict__ enc_states,  // [B][T][H]
    const float* __restrict__ dec_hs,      // [B][T][H]
    const float* __restrict__ ew, const float* __restrict__ hw,
    const float* __restrict__ lin_b,
    float* __restrict__ out)               // [B][T]
{
    const int b   = blockIdx.y;
    const int td0 = blockIdx.x * TD2;
    const int tid = threadIdx.x;
    const int tdt = tid >> 5;   // 0..7 (4 td rows each)
    const int tet = tid & 31;   // 0..31

    __shared__ float Hx[HD][TD2 + 4];   // stride 36: rows 16B-aligned
    __shared__ float E[KC2][TEC2];

    // stage Hx: thread -> (td = tid>>3, 32-k chunk = (tid&7)*32)
    {
        const int td = tid >> 3;
        const int kc = (tid & 7) * 32;
        const float* src = dec_hs + ((size_t)b * TT + td0 + td) * HD + kc;
        #pragma unroll
        for (int qq = 0; qq < 8; ++qq) {
            float4 v = ((const float4*)(src + qq * 4))[0];
            Hx[kc + qq * 4 + 0][td] = v.x;
            Hx[kc + qq * 4 + 1][td] = v.y;
            Hx[kc + qq * 4 + 2][td] = v.z;
            Hx[kc + qq * 4 + 3][td] = v.w;
        }
    }

    float M[4]  = {-1e30f, -1e30f, -1e30f, -1e30f};
    float Nm[4] = {0.f, 0.f, 0.f, 0.f};
    float Dn[4] = {0.f, 0.f, 0.f, 0.f};

    for (int tc = 0; tc < TT / TEC2; ++tc) {
        const int te0 = tc * TEC2;
        float S[4][8] = {{0.f}};
        for (int kc = 0; kc < HD / KC2; ++kc) {
            const int k0 = kc * KC2;
            __syncthreads();
            {   // stage E chunk: thread = te row, 32 consecutive k
                const float* src = enc_states + ((size_t)b * TT + te0 + tid) * HD + k0;
                #pragma unroll
                for (int qq = 0; qq < 8; ++qq) {
                    float4 v = ((const float4*)(src + qq * 4))[0];
                    E[qq * 4 + 0][tid] = v.x;
                    E[qq * 4 + 1][tid] = v.y;
                    E[qq * 4 + 2][tid] = v.z;
                    E[qq * 4 + 3][tid] = v.w;
                }
            }
            __syncthreads();
            #pragma unroll 4
            for (int k = 0; k < KC2; ++k) {
                const float4 hx4 = *(const float4*)(&Hx[k0 + k][tdt * 4]);
                #pragma unroll
                for (int i = 0; i < 8; ++i) {
                    const float e = E[k][tet + 32 * i];
                    S[0][i] = fmaf(hx4.x, e, S[0][i]);
                    S[1][i] = fmaf(hx4.y, e, S[1][i]);
                    S[2][i] = fmaf(hx4.z, e, S[2][i]);
                    S[3][i] = fmaf(hx4.w, e, S[3][i]);
                }
            }
        }
        float ewv[8];
        #pragma unroll
        for (int i = 0; i < 8; ++i) ewv[i] = ew[(size_t)b * TT + te0 + tet + 32 * i];
        #pragma unroll
        for (int r = 0; r < 4; ++r) {
            float cm = S[r][0];
            #pragma unroll
            for (int i = 1; i < 8; ++i) cm = fmaxf(cm, S[r][i]);
            #pragma unroll
            for (int m = 1; m < 32; m <<= 1) cm = fmaxf(cm, __shfl_xor(cm, m));
            const float newM  = fmaxf(M[r], cm);
            const float scale = __expf(M[r] - newM);
            float nl = 0.f, dl = 0.f;
            #pragma unroll
            for (int i = 0; i < 8; ++i) {
                const float p = __expf(S[r][i] - newM);
                dl += p;
                nl = fmaf(p, ewv[i], nl);
            }
            #pragma unroll
            for (int m = 1; m < 32; m <<= 1) {
                nl += __shfl_xor(nl, m);
                dl += __shfl_xor(dl, m);
            }
            Nm[r] = Nm[r] * scale + nl;
            Dn[r] = Dn[r] * scale + dl;
            M[r]  = newM;
        }
    }

    if (tet == 0) {
        const float lb = lin_b[0];
        #pragma unroll
        for (int r = 0; r < 4; ++r) {
            const int td = td0 + tdt * 4 + r;
            out[(size_t)b * TT + td] = Nm[r] / Dn[r] + hw[(size_t)b * TT + td] + lb;
        }
    }
}

extern "C" void kernel_launch(void* const* d_in, const int* in_sizes, int n_in,
                              void* d_out, int out_size, void* d_ws, size_t ws_size,
                              hipStream_t stream)
{
    const float* x    = (const float*)d_in[0];
    const float* eWih = (const float*)d_in[1];
    const float* eWhh = (const float*)d_in[2];
    const float* ebih = (const float*)d_in[3];
    const float* ebhh = (const float*)d_in[4];
    const float* dWih = (const float*)d_in[5];
    const float* dWhh = (const float*)d_in[6];
    const float* dbih = (const float*)d_in[7];
    const float* dbhh = (const float*)d_in[8];
    const float* linW = (const float*)d_in[9];
    const float* linb = (const float*)d_in[10];
    float* out = (float*)d_out;

    float* p = (float*)d_ws;
    float* WTe = p;        p += (size_t)GD * HD;
    float* WTd = p;        p += (size_t)GD * HD;
    float* be  = p;        p += GD;
    float* bd  = p;        p += GD;
    float* enc_states = p; p += (size_t)BB * TT * HD;
    float* dec_hs = p;     p += (size_t)BB * TT * HD;
    float* ew = p;         p += (size_t)BB * TT;
    float* hw = p;         p += (size_t)BB * TT;
    unsigned long long* ex_e = (unsigned long long*)p; p += (size_t)BB * 2 * 256 * 2;
    unsigned long long* ex_d = (unsigned long long*)p; p += (size_t)BB * 2 * 256 * 2;

    prep_kernel<<<(GD * HD + 255) / 256, 256, 0, stream>>>(
        eWhh, ebih, ebhh, dWhh, dbih, dbhh, WTe, WTd, be, bd, ex_e);

    {
        const float* hi = nullptr;
        void* args[] = {(void*)&x, (void*)&eWih, (void*)&be, (void*)&WTe,
                        (void*)&hi, (void*)&enc_states, (void*)&ex_e};
        hipLaunchCooperativeKernel((void*)lstm_scan_coop, dim3(256), dim3(NT),
                                   args, 0, stream);
    }
    {
        const float* hi = enc_states;
        void* args[] = {(void*)&x, (void*)&dWih, (void*)&bd, (void*)&WTd,
                        (void*)&hi, (void*)&dec_hs, (void*)&ex_d};
        hipLaunchCooperativeKernel((void*)lstm_scan_coop, dim3(256), dim3(NT),
                                   args, 0, stream);
    }

    proj_kernel<<<256, 256, 0, stream>>>(enc_states, dec_hs, linW, ew, hw);
    attn_kernel<<<dim3(TT / TD2, BB), 256, 0, stream>>>(enc_states, dec_hs, ew, hw, linb, out);
}